// Round 4
// baseline (6946.272 us; speedup 1.0000x reference)
//
#include <hip/hip_runtime.h>
#include <math.h>

// ---------------------------------------------------------------------------
// GPT-2 small forward (B=8,T=1024,E=768,H=12,L=12,V=50304), last-pos logits.
// Round 4: inputs f32 (proven by round 1-3 NaN bisect), OUTPUT F32 (reference
// returns jnp.float32; round-3's 3.49 error matched bf16-written-into-f32-read
// exactly). Internal: bf16 MFMA GEMMs, f32 residual stream, f32 softmax/LN.
// ---------------------------------------------------------------------------

typedef unsigned short u16;
typedef __attribute__((ext_vector_type(8))) short short8;  // 8 bf16 in 4 VGPRs
typedef __attribute__((ext_vector_type(4))) float f32x4;

__device__ __forceinline__ float sane(float x) {
  return (fabsf(x) < 1.0e6f) ? x : 0.0f;
}
__device__ __forceinline__ u16 f2bf(float f) {
  union { float f; unsigned u; } x; x.f = f;
  unsigned r = x.u + 0x7FFFu + ((x.u >> 16) & 1u);  // round-to-nearest-even
  return (u16)(r >> 16);
}
__device__ __forceinline__ float bf2f(u16 v) {
  union { unsigned u; float f; } x; x.u = ((unsigned)v) << 16; return x.f;
}
__device__ __forceinline__ short8 pack8(f32x4 a, f32x4 b) {
  short8 r;
  r[0] = (short)f2bf(sane(a[0])); r[1] = (short)f2bf(sane(a[1]));
  r[2] = (short)f2bf(sane(a[2])); r[3] = (short)f2bf(sane(a[3]));
  r[4] = (short)f2bf(sane(b[0])); r[5] = (short)f2bf(sane(b[1]));
  r[6] = (short)f2bf(sane(b[2])); r[7] = (short)f2bf(sane(b[3]));
  return r;
}
__device__ __forceinline__ float gelu_exact(float v) {
  return 0.5f * v * (1.0f + erff(v * 0.70710678118654752440f));
}

// ---------------------------------------------------------------------------
// Embedding: x[b,t,:] = wte[idx[b,t],:] + wpe[t,:]  (f32 in, f32 out)
// ---------------------------------------------------------------------------
__global__ void embed_kernel(const int* __restrict__ idx,
                             const float* __restrict__ wte,
                             const float* __restrict__ wpe,
                             float* __restrict__ X) {
  const int token = blockIdx.x;           // 0..8191
  const int t = threadIdx.x;              // 256 threads
  const int id = idx[token];
  const int tpos = token & 1023;
  const size_t xo = (size_t)token * 768;
  const size_t wo = (size_t)id * 768;
  const size_t po = (size_t)tpos * 768;
#pragma unroll
  for (int j = 0; j < 3; j++) {
    const int e = t + j * 256;
    X[xo + e] = sane(wte[wo + e]) + sane(wpe[po + e]);
  }
}

// ---------------------------------------------------------------------------
// LayerNorm: one block per row; f32 in -> bf16 out.  eps=1e-5.
// ---------------------------------------------------------------------------
__global__ void ln_kernel(const float* __restrict__ X,
                          const float* __restrict__ w,
                          const float* __restrict__ b,
                          u16* __restrict__ Hout) {
  const int row = blockIdx.x;
  const int t = threadIdx.x;
  const float* xr = X + (size_t)row * 768;
  float v0 = xr[t], v1 = xr[t + 256], v2 = xr[t + 512];
  float s = v0 + v1 + v2;
  float s2 = v0 * v0 + v1 * v1 + v2 * v2;
#pragma unroll
  for (int d = 32; d > 0; d >>= 1) {
    s += __shfl_down(s, d, 64);
    s2 += __shfl_down(s2, d, 64);
  }
  __shared__ float red[8];
  __shared__ float stats[2];
  const int wv = t >> 6, lane = t & 63;
  if (lane == 0) { red[wv] = s; red[wv + 4] = s2; }
  __syncthreads();
  if (t == 0) {
    float S = red[0] + red[1] + red[2] + red[3];
    float S2 = red[4] + red[5] + red[6] + red[7];
    float mu = S * (1.0f / 768.0f);
    float var = S2 * (1.0f / 768.0f) - mu * mu;
    stats[0] = mu;
    stats[1] = 1.0f / sqrtf(fmaxf(var, 0.0f) + 1e-5f);
  }
  __syncthreads();
  const float mu = stats[0], inv = stats[1];
  u16* hr = Hout + (size_t)row * 768;
  const float vv[3] = {v0, v1, v2};
#pragma unroll
  for (int j = 0; j < 3; j++) {
    const int e = t + j * 256;
    hr[e] = f2bf((vv[j] - mu) * inv * sane(w[e]) + sane(b[e]));
  }
}

// ---------------------------------------------------------------------------
// Final LN on the 8 last-position rows -> XF[128,768] bf16 (rows 8..127 zero).
// ---------------------------------------------------------------------------
__global__ void lnf_kernel(const float* __restrict__ X,
                           const float* __restrict__ w,
                           const float* __restrict__ b,
                           u16* __restrict__ XF) {
  const int r = blockIdx.x;  // 0..127
  const int t = threadIdx.x;
  u16* outr = XF + (size_t)r * 768;
  if (r >= 8) {
#pragma unroll
    for (int j = 0; j < 3; j++) outr[t + j * 256] = 0;
    return;
  }
  const int row = r * 1024 + 1023;
  const float* xr = X + (size_t)row * 768;
  float v0 = xr[t], v1 = xr[t + 256], v2 = xr[t + 512];
  float s = v0 + v1 + v2;
  float s2 = v0 * v0 + v1 * v1 + v2 * v2;
#pragma unroll
  for (int d = 32; d > 0; d >>= 1) {
    s += __shfl_down(s, d, 64);
    s2 += __shfl_down(s2, d, 64);
  }
  __shared__ float red[8];
  __shared__ float stats[2];
  const int wv = t >> 6, lane = t & 63;
  if (lane == 0) { red[wv] = s; red[wv + 4] = s2; }
  __syncthreads();
  if (t == 0) {
    float S = red[0] + red[1] + red[2] + red[3];
    float S2 = red[4] + red[5] + red[6] + red[7];
    float mu = S * (1.0f / 768.0f);
    float var = S2 * (1.0f / 768.0f) - mu * mu;
    stats[0] = mu;
    stats[1] = 1.0f / sqrtf(fmaxf(var, 0.0f) + 1e-5f);
  }
  __syncthreads();
  const float mu = stats[0], inv = stats[1];
  const float vv[3] = {v0, v1, v2};
#pragma unroll
  for (int j = 0; j < 3; j++) {
    const int e = t + j * 256;
    outr[e] = f2bf((vv[j] - mu) * inv * sane(w[e]) + sane(b[e]));
  }
}

// ---------------------------------------------------------------------------
// GEMM: C[M,N] = A[M,K] (bf16, ours) @ Bw[N,K]^T (f32 input, cvt->bf16) + bias
// EPI 0: store bf16 (rows < M_valid)   EPI 1: gelu then store bf16
// EPI 2: X[M,N] (f32) += result        (residual accumulate, in-place)
// EPI 3: X[M,N] (f32) = result, rows < M_valid   (f32 logits store)
// 128x128 tile, BK=32, 256 threads (4 waves, each 64x64 = 4x4 MFMAs).
// ---------------------------------------------------------------------------
template <int EPI>
__global__ __launch_bounds__(256) void gemm_bt(
    const u16* __restrict__ A, const float* __restrict__ Bw,
    const float* __restrict__ bias, u16* __restrict__ C,
    float* __restrict__ X, int M, int N, int K, int M_valid) {
  __shared__ alignas(16) u16 As[128 * 32];
  __shared__ alignas(16) u16 Bs[128 * 32];
  const int t = threadIdx.x;
  const int w = t >> 6, lane = t & 63, quad = lane >> 4, l16 = lane & 15;
  const int m0 = blockIdx.x * 128, n0 = blockIdx.y * 128;
  const int wm = (w & 1) * 64, wn = (w >> 1) * 64;

  f32x4 acc[4][4] = {};

  // staging map: rows r0 (0..63) and r1=r0+64, cols c0..c0+7 (8 elems/thread)
  const int r0 = t >> 2, c0 = (t & 3) * 8;
  const int r1 = 64 + r0;
  const u16* gA0 = A + (size_t)(m0 + r0) * K + c0;
  const u16* gA1 = A + (size_t)(m0 + r1) * K + c0;
  const float* gB0 = Bw + (size_t)(n0 + r0) * K + c0;
  const float* gB1 = Bw + (size_t)(n0 + r1) * K + c0;

  for (int k0 = 0; k0 < K; k0 += 32) {
    const short8 a0 = *(const short8*)(gA0 + k0);
    const short8 a1 = *(const short8*)(gA1 + k0);
    const f32x4 b0a = *(const f32x4*)(gB0 + k0);
    const f32x4 b0b = *(const f32x4*)(gB0 + k0 + 4);
    const f32x4 b1a = *(const f32x4*)(gB1 + k0);
    const f32x4 b1b = *(const f32x4*)(gB1 + k0 + 4);
    const short8 b0 = pack8(b0a, b0b);
    const short8 b1 = pack8(b1a, b1b);
    __syncthreads();  // prior iteration's LDS reads complete before overwrite
    *(short8*)&As[r0 * 32 + c0] = a0;
    *(short8*)&As[r1 * 32 + c0] = a1;
    *(short8*)&Bs[r0 * 32 + c0] = b0;
    *(short8*)&Bs[r1 * 32 + c0] = b1;
    __syncthreads();  // publish staged tile

    short8 af[4], bb[4];
#pragma unroll
    for (int i = 0; i < 4; i++)
      af[i] = *(const short8*)&As[(wm + i * 16 + l16) * 32 + quad * 8];
#pragma unroll
    for (int j = 0; j < 4; j++)
      bb[j] = *(const short8*)&Bs[(wn + j * 16 + l16) * 32 + quad * 8];
#pragma unroll
    for (int i = 0; i < 4; i++)
#pragma unroll
      for (int j = 0; j < 4; j++)
        acc[i][j] = __builtin_amdgcn_mfma_f32_16x16x32_bf16(af[i], bb[j],
                                                            acc[i][j], 0, 0, 0);
  }

#pragma unroll
  for (int j = 0; j < 4; j++) {
    const int col = n0 + wn + j * 16 + l16;
    const float bv = sane(bias[col]);
#pragma unroll
    for (int i = 0; i < 4; i++) {
      const int rowb = m0 + wm + i * 16 + quad * 4;
#pragma unroll
      for (int r = 0; r < 4; r++) {
        const int row = rowb + r;
        float v = acc[i][j][r] + bv;
        if constexpr (EPI == 1) v = gelu_exact(v);
        if constexpr (EPI == 2) {
          X[(size_t)row * N + col] += v;
        } else if constexpr (EPI == 3) {
          if (row < M_valid) X[(size_t)row * N + col] = v;
        } else {
          if (row < M_valid) C[(size_t)row * N + col] = f2bf(v);
        }
      }
    }
  }
}

// ---------------------------------------------------------------------------
// Flash attention (faithful: split order k,q,v; NO 1/sqrt(d) scale; causal).
// qkv: [8192, 2304] bf16 rows (b*1024+t), ours.  Y: [8192, 768] bf16.
// Grid (16 qtiles, 96 bh). 4 waves/block, 16 queries/wave, 32-key blocks.
// ---------------------------------------------------------------------------
__global__ __launch_bounds__(256) void attn_kernel(const u16* __restrict__ qkv,
                                                   u16* __restrict__ Y) {
  __shared__ alignas(16) u16 Ks[32 * 64];      // [key][d]
  __shared__ alignas(16) u16 Vt[64 * 32];      // [d][key] (transposed)
  __shared__ alignas(16) u16 Ps[4][16 * 32];   // per-wave P tile [q][key]
  const int t = threadIdx.x, w = t >> 6, lane = t & 63;
  const int quad = lane >> 4, l16 = lane & 15;
  const int qt = blockIdx.x;   // 0..15
  const int bh = blockIdx.y;   // 0..95
  const int b = bh / 12, h = bh % 12;
  const size_t base = (size_t)b * 1024 * 2304;
  const int kcol = h * 64, qcol = 768 + h * 64, vcol = 1536 + h * 64;

  // Q fragments (A-operand): rows qt*64 + w*16 + l16, d = half*32 + quad*8 + j
  const int qrow = qt * 64 + w * 16 + l16;
  const u16* qp = qkv + base + (size_t)qrow * 2304 + qcol;
  const short8 qf0 = *(const short8*)(qp + quad * 8);
  const short8 qf1 = *(const short8*)(qp + 32 + quad * 8);

  f32x4 o0 = {}, o1 = {}, o2 = {}, o3 = {};
  float mrun[4], lrun[4];
#pragma unroll
  for (int r = 0; r < 4; r++) { mrun[r] = -1.0e30f; lrun[r] = 0.0f; }

  const int skey = t >> 3, sdc = (t & 7) * 8;  // staging: key row, d offset
  const int nkb = qt * 2 + 2;                  // key blocks 0..(qt*64+63)
  for (int kb = 0; kb < nkb; kb++) {
    const int k0 = kb * 32;
    const u16* kvrow = qkv + base + (size_t)(k0 + skey) * 2304;
    const short8 kk = *(const short8*)(kvrow + kcol + sdc);
    const short8 vv = *(const short8*)(kvrow + vcol + sdc);
    __syncthreads();  // prior iteration's Ks/Vt readers done
    *(short8*)&Ks[skey * 64 + sdc] = kk;
#pragma unroll
    for (int j = 0; j < 8; j++) Vt[(sdc + j) * 32 + skey] = ((const u16*)&vv)[j];
    __syncthreads();  // publish

    // S = Q K^T  (two 16-key tiles, contraction over d=64 in two halves)
    f32x4 s[2];
#pragma unroll
    for (int kt = 0; kt < 2; kt++) {
      const short8 kf0 = *(const short8*)&Ks[(kt * 16 + l16) * 64 + quad * 8];
      const short8 kf1 = *(const short8*)&Ks[(kt * 16 + l16) * 64 + 32 + quad * 8];
      f32x4 z = {};
      z = __builtin_amdgcn_mfma_f32_16x16x32_bf16(qf0, kf0, z, 0, 0, 0);
      z = __builtin_amdgcn_mfma_f32_16x16x32_bf16(qf1, kf1, z, 0, 0, 0);
      s[kt] = z;
    }

    // online softmax per row (row = quad*4 + r, cols spread over l16)
    const int qbase = qt * 64 + w * 16 + quad * 4;
#pragma unroll
    for (int r = 0; r < 4; r++) {
      const int qg = qbase + r;
      const bool ok0 = (k0 + l16 <= qg);
      const bool ok1 = (k0 + 16 + l16 <= qg);
      const float s0 = ok0 ? s[0][r] : -1.0e30f;
      const float s1 = ok1 ? s[1][r] : -1.0e30f;
      float mx = fmaxf(s0, s1);
#pragma unroll
      for (int d = 1; d < 16; d <<= 1) mx = fmaxf(mx, __shfl_xor(mx, d, 64));
      const float mnew = fmaxf(mrun[r], mx);
      const float p0 = ok0 ? expf(s0 - mnew) : 0.0f;
      const float p1 = ok1 ? expf(s1 - mnew) : 0.0f;
      float ps = p0 + p1;
#pragma unroll
      for (int d = 1; d < 16; d <<= 1) ps += __shfl_xor(ps, d, 64);
      const float alpha = expf(mrun[r] - mnew);
      lrun[r] = lrun[r] * alpha + ps;
      mrun[r] = mnew;
      Ps[w][(quad * 4 + r) * 32 + l16] = f2bf(p0);
      Ps[w][(quad * 4 + r) * 32 + 16 + l16] = f2bf(p1);
      o0[r] *= alpha; o1[r] *= alpha; o2[r] *= alpha; o3[r] *= alpha;
    }

    // P (C-layout) -> A-operand layout via per-wave LDS round-trip
    const short8 pa = *(const short8*)&Ps[w][l16 * 32 + quad * 8];
    const short8 vf0 = *(const short8*)&Vt[(0 * 16 + l16) * 32 + quad * 8];
    const short8 vf1 = *(const short8*)&Vt[(1 * 16 + l16) * 32 + quad * 8];
    const short8 vf2 = *(const short8*)&Vt[(2 * 16 + l16) * 32 + quad * 8];
    const short8 vf3 = *(const short8*)&Vt[(3 * 16 + l16) * 32 + quad * 8];
    o0 = __builtin_amdgcn_mfma_f32_16x16x32_bf16(pa, vf0, o0, 0, 0, 0);
    o1 = __builtin_amdgcn_mfma_f32_16x16x32_bf16(pa, vf1, o1, 0, 0, 0);
    o2 = __builtin_amdgcn_mfma_f32_16x16x32_bf16(pa, vf2, o2, 0, 0, 0);
    o3 = __builtin_amdgcn_mfma_f32_16x16x32_bf16(pa, vf3, o3, 0, 0, 0);
  }

  // epilogue: O /= l, store bf16
  const f32x4 oo[4] = {o0, o1, o2, o3};
#pragma unroll
  for (int r = 0; r < 4; r++) {
    const float inv_l = 1.0f / fmaxf(lrun[r], 1e-20f);
    const int row = qt * 64 + w * 16 + quad * 4 + r;
#pragma unroll
    for (int dt = 0; dt < 4; dt++) {
      const float v = oo[dt][r] * inv_l;
      Y[((size_t)(b * 1024 + row)) * 768 + h * 64 + dt * 16 + l16] = f2bf(v);
    }
  }
}

// ---------------------------------------------------------------------------
// Host launch
// ---------------------------------------------------------------------------
extern "C" void kernel_launch(void* const* d_in, const int* in_sizes, int n_in,
                              void* d_out, int out_size, void* d_ws,
                              size_t ws_size, hipStream_t stream) {
  const int* idx = (const int*)d_in[0];
  const float* wte = (const float*)d_in[1];
  const float* wpe = (const float*)d_in[2];
  const float* qkv_w = (const float*)d_in[3];
  const float* qkv_b = (const float*)d_in[4];
  const float* proj_w = (const float*)d_in[5];
  const float* proj_b = (const float*)d_in[6];
  const float* ln_w = (const float*)d_in[7];
  const float* ln_b = (const float*)d_in[8];
  const float* c1_w = (const float*)d_in[9];
  const float* c1_b = (const float*)d_in[10];
  const float* c2_w = (const float*)d_in[11];
  const float* c2_b = (const float*)d_in[12];
  const float* lnf_w = (const float*)d_in[13];
  const float* lnf_b = (const float*)d_in[14];
  const float* lm_b = (const float*)d_in[15];
  float* out = (float*)d_out;   // reference output dtype is float32

  // workspace layout (U aliases the dead QKV+Y region): total ~84.2 MiB
  char* ws = (char*)d_ws;
  float* X = (float*)(ws + 0);              // [8192,768] f32   25165824 B
  u16* Hb = (u16*)(ws + 25165824);          // [8192,768] bf16  12582912 B
  u16* QKV = (u16*)(ws + 37748736);         // [8192,2304] bf16 37748736 B
  u16* Yb = (u16*)(ws + 75497472);          // [8192,768] bf16  12582912 B
  u16* Ub = (u16*)(ws + 37748736);          // [8192,3072] bf16 (aliases QKV+Y)
  u16* XF = (u16*)(ws + 88080384);          // [128,768] bf16     196608 B

  embed_kernel<<<8192, 256, 0, stream>>>(idx, wte, wpe, X);

  for (int l = 0; l < 12; l++) {
    const float* qw = qkv_w + (size_t)l * 2304 * 768;
    const float* qb = qkv_b + (size_t)l * 2304;
    const float* pw = proj_w + (size_t)l * 768 * 768;
    const float* pb = proj_b + (size_t)l * 768;
    const float* lw = ln_w + (size_t)l * 768;
    const float* lb = ln_b + (size_t)l * 768;
    const float* w1 = c1_w + (size_t)l * 3072 * 768;
    const float* b1 = c1_b + (size_t)l * 3072;
    const float* w2 = c2_w + (size_t)l * 768 * 3072;
    const float* b2 = c2_b + (size_t)l * 768;

    ln_kernel<<<8192, 256, 0, stream>>>(X, lw, lb, Hb);
    gemm_bt<0><<<dim3(64, 18), 256, 0, stream>>>(Hb, qw, qb, QKV, nullptr,
                                                 8192, 2304, 768, 8192);
    attn_kernel<<<dim3(16, 96), 256, 0, stream>>>(QKV, Yb);
    gemm_bt<2><<<dim3(64, 6), 256, 0, stream>>>(Yb, pw, pb, nullptr, X,
                                                8192, 768, 768, 8192);
    ln_kernel<<<8192, 256, 0, stream>>>(X, lw, lb, Hb);
    gemm_bt<1><<<dim3(64, 24), 256, 0, stream>>>(Hb, w1, b1, Ub, nullptr,
                                                 8192, 3072, 768, 8192);
    gemm_bt<2><<<dim3(64, 6), 256, 0, stream>>>(Ub, w2, b2, nullptr, X,
                                                8192, 768, 3072, 8192);
  }

  lnf_kernel<<<128, 256, 0, stream>>>(X, lnf_w, lnf_b, XF);
  gemm_bt<3><<<dim3(1, 393), 256, 0, stream>>>(XF, wte, lm_b, nullptr, out,
                                               128, 50304, 768, 8);
}

// Round 5
// 4565.332 us; speedup vs baseline: 1.5215x; 1.5215x over previous
//
#include <hip/hip_runtime.h>
#include <math.h>

// ---------------------------------------------------------------------------
// GPT-2 small forward (B=8,T=1024,E=768,H=12,L=12,V=50304), last-pos logits.
// Round 5: (1) attention rewrite — S^T=K·Q^T so q lives on l16, unnormalized
// exp2 accumulation (no online max, no in-loop shuffles), 64-key staging,
// m97-layout Ks; (2) per-layer bf16 weight pre-convert + global_load_lds
// width-16 GEMM staging (m97 structure); (3) 64x128 tiles for N=768 GEMMs.
// ---------------------------------------------------------------------------

typedef unsigned short u16;
typedef unsigned int u32;
typedef __attribute__((ext_vector_type(8))) short short8;  // 8 bf16 in 4 VGPRs
typedef __attribute__((ext_vector_type(4))) float f32x4;

__device__ __forceinline__ float sane(float x) {
  return (fabsf(x) < 1.0e6f) ? x : 0.0f;
}
__device__ __forceinline__ u16 f2bf(float f) {
  union { float f; unsigned u; } x; x.f = f;
  unsigned r = x.u + 0x7FFFu + ((x.u >> 16) & 1u);  // round-to-nearest-even
  return (u16)(r >> 16);
}
__device__ __forceinline__ short8 pack8(f32x4 a, f32x4 b) {
  short8 r;
  r[0] = (short)f2bf(sane(a[0])); r[1] = (short)f2bf(sane(a[1]));
  r[2] = (short)f2bf(sane(a[2])); r[3] = (short)f2bf(sane(a[3]));
  r[4] = (short)f2bf(sane(b[0])); r[5] = (short)f2bf(sane(b[1]));
  r[6] = (short)f2bf(sane(b[2])); r[7] = (short)f2bf(sane(b[3]));
  return r;
}
__device__ __forceinline__ float gelu_exact(float v) {
  return 0.5f * v * (1.0f + erff(v * 0.70710678118654752440f));
}
__device__ __forceinline__ void async16(const void* g, void* l) {
  __builtin_amdgcn_global_load_lds(
      (const __attribute__((address_space(1))) unsigned*)g,
      (__attribute__((address_space(3))) unsigned*)l, 16, 0, 0);
}

// ---------------------------------------------------------------------------
// Per-layer weight convert f32 -> bf16: [qkv | proj | c1 | c2] contiguous.
// sizes: 1769472, 589824, 2359296, 2359296  (total 7077888, all %8==0)
// ---------------------------------------------------------------------------
__global__ void wconv_kernel(const float* __restrict__ qw,
                             const float* __restrict__ pw,
                             const float* __restrict__ w1,
                             const float* __restrict__ w2,
                             u16* __restrict__ Wb) {
  const size_t i = ((size_t)blockIdx.x * 256 + threadIdx.x) * 8;
  const float* src; size_t off;
  if (i < 1769472) { src = qw; off = i; }
  else if (i < 2359296) { src = pw; off = i - 1769472; }
  else if (i < 4718592) { src = w1; off = i - 2359296; }
  else { src = w2; off = i - 4718592; }
  const f32x4 a = *(const f32x4*)(src + off);
  const f32x4 b = *(const f32x4*)(src + off + 4);
  *(short8*)(Wb + i) = pack8(a, b);
}

// ---------------------------------------------------------------------------
// Embedding: x[b,t,:] = wte[idx[b,t],:] + wpe[t,:]  (f32 out)
// ---------------------------------------------------------------------------
__global__ void embed_kernel(const int* __restrict__ idx,
                             const float* __restrict__ wte,
                             const float* __restrict__ wpe,
                             float* __restrict__ X) {
  const int token = blockIdx.x;
  const int t = threadIdx.x;
  const int id = idx[token];
  const int tpos = token & 1023;
  const size_t xo = (size_t)token * 768;
  const size_t wo = (size_t)id * 768;
  const size_t po = (size_t)tpos * 768;
#pragma unroll
  for (int j = 0; j < 3; j++) {
    const int e = t + j * 256;
    X[xo + e] = sane(wte[wo + e]) + sane(wpe[po + e]);
  }
}

// ---------------------------------------------------------------------------
// LayerNorm: one block per row; f32 in -> bf16 out.  eps=1e-5.
// ---------------------------------------------------------------------------
__global__ void ln_kernel(const float* __restrict__ X,
                          const float* __restrict__ w,
                          const float* __restrict__ b,
                          u16* __restrict__ Hout) {
  const int row = blockIdx.x;
  const int t = threadIdx.x;
  const float* xr = X + (size_t)row * 768;
  float v0 = xr[t], v1 = xr[t + 256], v2 = xr[t + 512];
  float s = v0 + v1 + v2;
  float s2 = v0 * v0 + v1 * v1 + v2 * v2;
#pragma unroll
  for (int d = 32; d > 0; d >>= 1) {
    s += __shfl_down(s, d, 64);
    s2 += __shfl_down(s2, d, 64);
  }
  __shared__ float red[8];
  __shared__ float stats[2];
  const int wv = t >> 6, lane = t & 63;
  if (lane == 0) { red[wv] = s; red[wv + 4] = s2; }
  __syncthreads();
  if (t == 0) {
    float S = red[0] + red[1] + red[2] + red[3];
    float S2 = red[4] + red[5] + red[6] + red[7];
    float mu = S * (1.0f / 768.0f);
    float var = S2 * (1.0f / 768.0f) - mu * mu;
    stats[0] = mu;
    stats[1] = 1.0f / sqrtf(fmaxf(var, 0.0f) + 1e-5f);
  }
  __syncthreads();
  const float mu = stats[0], inv = stats[1];
  u16* hr = Hout + (size_t)row * 768;
  const float vv[3] = {v0, v1, v2};
#pragma unroll
  for (int j = 0; j < 3; j++) {
    const int e = t + j * 256;
    hr[e] = f2bf((vv[j] - mu) * inv * sane(w[e]) + sane(b[e]));
  }
}

// ---------------------------------------------------------------------------
// Final LN on the 8 last-position rows -> XF[128,768] bf16 (rows 8..127 zero).
// ---------------------------------------------------------------------------
__global__ void lnf_kernel(const float* __restrict__ X,
                           const float* __restrict__ w,
                           const float* __restrict__ b,
                           u16* __restrict__ XF) {
  const int r = blockIdx.x;
  const int t = threadIdx.x;
  u16* outr = XF + (size_t)r * 768;
  if (r >= 8) {
#pragma unroll
    for (int j = 0; j < 3; j++) outr[t + j * 256] = 0;
    return;
  }
  const int row = r * 1024 + 1023;
  const float* xr = X + (size_t)row * 768;
  float v0 = xr[t], v1 = xr[t + 256], v2 = xr[t + 512];
  float s = v0 + v1 + v2;
  float s2 = v0 * v0 + v1 * v1 + v2 * v2;
#pragma unroll
  for (int d = 32; d > 0; d >>= 1) {
    s += __shfl_down(s, d, 64);
    s2 += __shfl_down(s2, d, 64);
  }
  __shared__ float red[8];
  __shared__ float stats[2];
  const int wv = t >> 6, lane = t & 63;
  if (lane == 0) { red[wv] = s; red[wv + 4] = s2; }
  __syncthreads();
  if (t == 0) {
    float S = red[0] + red[1] + red[2] + red[3];
    float S2 = red[4] + red[5] + red[6] + red[7];
    float mu = S * (1.0f / 768.0f);
    float var = S2 * (1.0f / 768.0f) - mu * mu;
    stats[0] = mu;
    stats[1] = 1.0f / sqrtf(fmaxf(var, 0.0f) + 1e-5f);
  }
  __syncthreads();
  const float mu = stats[0], inv = stats[1];
  const float vv[3] = {v0, v1, v2};
#pragma unroll
  for (int j = 0; j < 3; j++) {
    const int e = t + j * 256;
    outr[e] = f2bf((vv[j] - mu) * inv * sane(w[e]) + sane(b[e]));
  }
}

// ---------------------------------------------------------------------------
// GEMM (bf16 A, bf16 B): C[M,N] = A[M,K] @ Bw[N,K]^T + bias
// global_load_lds width-16 staging (m97). TM = 128 or 64; N-tile fixed 128.
// EPI 0: bf16 store  EPI 1: gelu+bf16 store  EPI 2: f32 X +=  (residual)
// ---------------------------------------------------------------------------
template <int EPI, int TM>
__global__ __launch_bounds__(256) void gemm_bt(
    const u16* __restrict__ A, const u16* __restrict__ Bw,
    const float* __restrict__ bias, u16* __restrict__ C,
    float* __restrict__ X, int M, int N, int K, int M_valid) {
  __shared__ alignas(16) u16 As[TM * 32];
  __shared__ alignas(16) u16 Bs[128 * 32];
  const int t = threadIdx.x;
  const int w = t >> 6, lane = t & 63, quad = lane >> 4, l16 = lane & 15;
  const int m0 = blockIdx.x * TM, n0 = blockIdx.y * 128;
  const int wm = (w & 1) * (TM / 2), wn = (w >> 1) * 64;
  constexpr int MI = TM / 32;  // 4 or 2 m-frags per wave

  f32x4 acc[MI][4] = {};

  // staging: rows t>>2 (+64), cols (t&3)*8; LDS dest = wave-uniform + lane*16
  const int r0 = t >> 2, c0 = (t & 3) * 8;
  const u16* gA0 = A + (size_t)(m0 + r0) * K + c0;
  const u16* gA1 = A + (size_t)(m0 + 64 + r0) * K + c0;  // TM==128 only
  const u16* gB0 = Bw + (size_t)(n0 + r0) * K + c0;
  const u16* gB1 = Bw + (size_t)(n0 + 64 + r0) * K + c0;
  u16* lA0 = &As[w * 512];
  u16* lA1 = &As[2048 + w * 512];
  u16* lB0 = &Bs[w * 512];
  u16* lB1 = &Bs[2048 + w * 512];

  for (int k0 = 0; k0 < K; k0 += 32) {
    async16(gA0 + k0, lA0);
    if constexpr (TM == 128) async16(gA1 + k0, lA1);
    async16(gB0 + k0, lB0);
    async16(gB1 + k0, lB1);
    __syncthreads();  // drains vmcnt (global_load_lds) + syncs all waves

    short8 af[MI], bb[4];
#pragma unroll
    for (int i = 0; i < MI; i++)
      af[i] = *(const short8*)&As[(wm + i * 16 + l16) * 32 + quad * 8];
#pragma unroll
    for (int j = 0; j < 4; j++)
      bb[j] = *(const short8*)&Bs[(wn + j * 16 + l16) * 32 + quad * 8];
#pragma unroll
    for (int i = 0; i < MI; i++)
#pragma unroll
      for (int j = 0; j < 4; j++)
        acc[i][j] = __builtin_amdgcn_mfma_f32_16x16x32_bf16(af[i], bb[j],
                                                            acc[i][j], 0, 0, 0);
    __syncthreads();  // all LDS reads done before next stage overwrites
  }

#pragma unroll
  for (int j = 0; j < 4; j++) {
    const int col = n0 + wn + j * 16 + l16;
    const float bv = sane(bias[col]);
#pragma unroll
    for (int i = 0; i < MI; i++) {
      const int rowb = m0 + wm + i * 16 + quad * 4;
#pragma unroll
      for (int r = 0; r < 4; r++) {
        const int row = rowb + r;
        float v = acc[i][j][r] + bv;
        if constexpr (EPI == 1) v = gelu_exact(v);
        if constexpr (EPI == 2) {
          X[(size_t)row * N + col] += v;
        } else {
          if (row < M_valid) C[(size_t)row * N + col] = f2bf(v);
        }
      }
    }
  }
}

// ---------------------------------------------------------------------------
// Logits GEMM: out[M,N] (f32) = A[M,K] (bf16) @ Bw[N,K]^T (f32->bf16) + bias
// Manual staging (one dispatch; wte stays f32). rows < M_valid stored.
// ---------------------------------------------------------------------------
__global__ __launch_bounds__(256) void gemm_logits(
    const u16* __restrict__ A, const float* __restrict__ Bw,
    const float* __restrict__ bias, float* __restrict__ Out,
    int M, int N, int K, int M_valid) {
  __shared__ alignas(16) u16 As[128 * 32];
  __shared__ alignas(16) u16 Bs[128 * 32];
  const int t = threadIdx.x;
  const int w = t >> 6, lane = t & 63, quad = lane >> 4, l16 = lane & 15;
  const int m0 = blockIdx.x * 128, n0 = blockIdx.y * 128;
  const int wm = (w & 1) * 64, wn = (w >> 1) * 64;
  f32x4 acc[4][4] = {};
  const int r0 = t >> 2, c0 = (t & 3) * 8;
  const u16* gA0 = A + (size_t)(m0 + r0) * K + c0;
  const u16* gA1 = A + (size_t)(m0 + 64 + r0) * K + c0;
  const float* gB0 = Bw + (size_t)(n0 + r0) * K + c0;
  const float* gB1 = Bw + (size_t)(n0 + 64 + r0) * K + c0;

  for (int k0 = 0; k0 < K; k0 += 32) {
    const short8 a0 = *(const short8*)(gA0 + k0);
    const short8 a1 = *(const short8*)(gA1 + k0);
    const short8 b0 = pack8(*(const f32x4*)(gB0 + k0), *(const f32x4*)(gB0 + k0 + 4));
    const short8 b1 = pack8(*(const f32x4*)(gB1 + k0), *(const f32x4*)(gB1 + k0 + 4));
    __syncthreads();
    *(short8*)&As[r0 * 32 + c0] = a0;
    *(short8*)&As[(64 + r0) * 32 + c0] = a1;
    *(short8*)&Bs[r0 * 32 + c0] = b0;
    *(short8*)&Bs[(64 + r0) * 32 + c0] = b1;
    __syncthreads();
    short8 af[4], bb[4];
#pragma unroll
    for (int i = 0; i < 4; i++)
      af[i] = *(const short8*)&As[(wm + i * 16 + l16) * 32 + quad * 8];
#pragma unroll
    for (int j = 0; j < 4; j++)
      bb[j] = *(const short8*)&Bs[(wn + j * 16 + l16) * 32 + quad * 8];
#pragma unroll
    for (int i = 0; i < 4; i++)
#pragma unroll
      for (int j = 0; j < 4; j++)
        acc[i][j] = __builtin_amdgcn_mfma_f32_16x16x32_bf16(af[i], bb[j],
                                                            acc[i][j], 0, 0, 0);
  }
#pragma unroll
  for (int j = 0; j < 4; j++) {
    const int col = n0 + wn + j * 16 + l16;
    const float bv = sane(bias[col]);
#pragma unroll
    for (int i = 0; i < 4; i++) {
      const int rowb = m0 + wm + i * 16 + quad * 4;
#pragma unroll
      for (int r = 0; r < 4; r++) {
        const int row = rowb + r;
        if (row < M_valid) Out[(size_t)row * N + col] = acc[i][j][r] + bv;
      }
    }
  }
}

// ---------------------------------------------------------------------------
// Flash attention, S^T formulation (faithful: k,q,v split order, NO 1/sqrt(d),
// causal). Unnormalized exp2 accumulation: no online max, no in-loop shuffles.
// qkv: [8192,2304] bf16.  Y: [8192,768] bf16.  Grid (16 qt, 96 bh), 4 waves.
// Per wave: 16 queries (q = l16 in S^T).  64 keys staged per barrier pair.
// ---------------------------------------------------------------------------
__global__ __launch_bounds__(256) void attn_kernel(const u16* __restrict__ qkv,
                                                   u16* __restrict__ Y) {
  __shared__ alignas(16) u16 Ks[2 * 2 * 32 * 32];  // [c][half][key][32d] 8 KB
  __shared__ alignas(16) u16 Vt[2 * 64 * 32];      // [c][d][key]         8 KB
  __shared__ alignas(16) u16 Ps[4][16 * 32];       // per-wave P [q][key]  4 KB
  const int t = threadIdx.x, w = t >> 6, lane = t & 63;
  const int quad = lane >> 4, l16 = lane & 15;
  const int qt = blockIdx.x;   // 0..15
  const int bh = blockIdx.y;   // 0..95
  const int b = bh / 12, h = bh % 12;
  const size_t base = (size_t)b * 1024 * 2304;
  const int kcol = h * 64, qcol = 768 + h * 64, vcol = 1536 + h * 64;

  // Q fragment (B-operand of K·Q^T): lane l16 = q, k-dim = d = quad*8+j
  const int qg = qt * 64 + w * 16 + l16;  // this lane's query row
  const u16* qp = qkv + base + (size_t)qg * 2304 + qcol;
  const short8 qf0 = *(const short8*)(qp + quad * 8);
  const short8 qf1 = *(const short8*)(qp + 32 + quad * 8);

  f32x4 o[4] = {};     // O[q=quad*4+r][d=dt*16+l16] accumulators
  float lpart = 0.0f;  // per-lane partial of l[q=l16]

  const int skey = t >> 3, sdc = (t & 7) * 8;
  const int nkb = qt + 1;  // 64-key groups, keys 0..qt*64+63
  for (int kb = 0; kb < nkb; kb++) {
    const int g0 = kb * 64;
    const u16* row0 = qkv + base + (size_t)(g0 + skey) * 2304;
    const u16* row1 = qkv + base + (size_t)(g0 + 32 + skey) * 2304;
    const short8 kk0 = *(const short8*)(row0 + kcol + sdc);
    const short8 vv0 = *(const short8*)(row0 + vcol + sdc);
    const short8 kk1 = *(const short8*)(row1 + kcol + sdc);
    const short8 vv1 = *(const short8*)(row1 + vcol + sdc);
    __syncthreads();  // prior iteration's readers done
    *(short8*)&Ks[(((0 * 2 + (sdc >> 5)) * 32 + skey) * 32) + (sdc & 31)] = kk0;
    *(short8*)&Ks[(((2 + (sdc >> 5)) * 32 + skey) * 32) + (sdc & 31)] = kk1;
#pragma unroll
    for (int j = 0; j < 8; j++) {
      Vt[(0 * 64 + sdc + j) * 32 + skey] = ((const u16*)&vv0)[j];
      Vt[(1 * 64 + sdc + j) * 32 + skey] = ((const u16*)&vv1)[j];
    }
    __syncthreads();  // publish

#pragma unroll
    for (int c = 0; c < 2; c++) {
      const int k0 = g0 + c * 32;
      // S^T = K · Q^T : two 16-key tiles, contraction over d in two halves
      u32* pw = (u32*)&Ps[w][0];
#pragma unroll
      for (int kt = 0; kt < 2; kt++) {
        const short8 af0 =
            *(const short8*)&Ks[((c * 2 + 0) * 32 + kt * 16 + l16) * 32 + quad * 8];
        const short8 af1 =
            *(const short8*)&Ks[((c * 2 + 1) * 32 + kt * 16 + l16) * 32 + quad * 8];
        f32x4 z = {};
        z = __builtin_amdgcn_mfma_f32_16x16x32_bf16(af0, qf0, z, 0, 0, 0);
        z = __builtin_amdgcn_mfma_f32_16x16x32_bf16(af1, qf1, z, 0, 0, 0);
        // lane holds S^T[key=k0+kt*16+quad*4+r][q=l16]
        float p[4];
#pragma unroll
        for (int r = 0; r < 4; r++) {
          const int key = k0 + kt * 16 + quad * 4 + r;
          p[r] = (key <= qg) ? exp2f(z[r] * 1.44269504088896f) : 0.0f;
          lpart += p[r];
        }
        const u32 u01 = (u32)f2bf(p[0]) | ((u32)f2bf(p[1]) << 16);
        const u32 u23 = (u32)f2bf(p[2]) | ((u32)f2bf(p[3]) << 16);
        pw[l16 * 16 + kt * 8 + quad * 2] = u01;
        pw[l16 * 16 + kt * 8 + quad * 2 + 1] = u23;
      }
      // P (A-operand, same-wave LDS roundtrip) and PV MFMAs
      const short8 pa = *(const short8*)&Ps[w][l16 * 32 + quad * 8];
#pragma unroll
      for (int dt = 0; dt < 4; dt++) {
        const short8 vf =
            *(const short8*)&Vt[(c * 64 + dt * 16 + l16) * 32 + quad * 8];
        o[dt] = __builtin_amdgcn_mfma_f32_16x16x32_bf16(pa, vf, o[dt], 0, 0, 0);
      }
    }
  }

  // epilogue: reduce l across the 4 lane-groups, redistribute, normalize, store
  float lf = lpart;
  lf += __shfl_xor(lf, 16, 64);
  lf += __shfl_xor(lf, 32, 64);  // lanes with same l16 now all hold l[q=l16]
#pragma unroll
  for (int r = 0; r < 4; r++) {
    const float linv = 1.0f / fmaxf(__shfl(lf, quad * 4 + r, 64), 1e-30f);
    const int row = qt * 64 + w * 16 + quad * 4 + r;
#pragma unroll
    for (int dt = 0; dt < 4; dt++) {
      Y[((size_t)(b * 1024 + row)) * 768 + h * 64 + dt * 16 + l16] =
          f2bf(o[dt][r] * linv);
    }
  }
}

// ---------------------------------------------------------------------------
// Host launch
// ---------------------------------------------------------------------------
extern "C" void kernel_launch(void* const* d_in, const int* in_sizes, int n_in,
                              void* d_out, int out_size, void* d_ws,
                              size_t ws_size, hipStream_t stream) {
  const int* idx = (const int*)d_in[0];
  const float* wte = (const float*)d_in[1];
  const float* wpe = (const float*)d_in[2];
  const float* qkv_w = (const float*)d_in[3];
  const float* qkv_b = (const float*)d_in[4];
  const float* proj_w = (const float*)d_in[5];
  const float* proj_b = (const float*)d_in[6];
  const float* ln_w = (const float*)d_in[7];
  const float* ln_b = (const float*)d_in[8];
  const float* c1_w = (const float*)d_in[9];
  const float* c1_b = (const float*)d_in[10];
  const float* c2_w = (const float*)d_in[11];
  const float* c2_b = (const float*)d_in[12];
  const float* lnf_w = (const float*)d_in[13];
  const float* lnf_b = (const float*)d_in[14];
  const float* lm_b = (const float*)d_in[15];
  float* out = (float*)d_out;

  // workspace: X | Hb | QKV | Yb | (Ub aliases QKV+Yb) | XF | Wb  (~97.7 MiB)
  char* ws = (char*)d_ws;
  float* X = (float*)(ws + 0);              // [8192,768] f32   25165824 B
  u16* Hb = (u16*)(ws + 25165824);          // [8192,768] bf16  12582912 B
  u16* QKV = (u16*)(ws + 37748736);         // [8192,2304] bf16 37748736 B
  u16* Yb = (u16*)(ws + 75497472);          // [8192,768] bf16  12582912 B
  u16* Ub = (u16*)(ws + 37748736);          // [8192,3072] bf16 (alias)
  u16* XF = (u16*)(ws + 88080384);          // [128,768] bf16     196608 B
  u16* Wb = (u16*)(ws + 88276992);          // [7077888] bf16   14155776 B

  const size_t WO_QKV = 0, WO_PROJ = 1769472, WO_C1 = 2359296, WO_C2 = 4718592;

  embed_kernel<<<8192, 256, 0, stream>>>(idx, wte, wpe, X);

  for (int l = 0; l < 12; l++) {
    const float* qw = qkv_w + (size_t)l * 2304 * 768;
    const float* qb = qkv_b + (size_t)l * 2304;
    const float* pw = proj_w + (size_t)l * 768 * 768;
    const float* pb = proj_b + (size_t)l * 768;
    const float* lw = ln_w + (size_t)l * 768;
    const float* lb = ln_b + (size_t)l * 768;
    const float* w1 = c1_w + (size_t)l * 3072 * 768;
    const float* b1 = c1_b + (size_t)l * 3072;
    const float* w2 = c2_w + (size_t)l * 768 * 3072;
    const float* b2 = c2_b + (size_t)l * 3072 / 4;  // = l*768

    wconv_kernel<<<3456, 256, 0, stream>>>(qw, pw, w1, w2, Wb);
    ln_kernel<<<8192, 256, 0, stream>>>(X, lw, lb, Hb);
    gemm_bt<0, 128><<<dim3(64, 18), 256, 0, stream>>>(
        Hb, Wb + WO_QKV, qb, QKV, nullptr, 8192, 2304, 768, 8192);
    attn_kernel<<<dim3(16, 96), 256, 0, stream>>>(QKV, Yb);
    gemm_bt<2, 64><<<dim3(128, 6), 256, 0, stream>>>(
        Yb, Wb + WO_PROJ, pb, nullptr, X, 8192, 768, 768, 8192);
    ln_kernel<<<8192, 256, 0, stream>>>(X, lw, lb, Hb);
    gemm_bt<1, 128><<<dim3(64, 24), 256, 0, stream>>>(
        Hb, Wb + WO_C1, b1, Ub, nullptr, 8192, 3072, 768, 8192);
    gemm_bt<2, 64><<<dim3(128, 6), 256, 0, stream>>>(
        Ub, Wb + WO_C2, b2, nullptr, X, 8192, 768, 3072, 8192);
  }

  lnf_kernel<<<128, 256, 0, stream>>>(X, lnf_w, lnf_b, XF);
  gemm_logits<<<dim3(1, 393), 256, 0, stream>>>(XF, wte, lm_b, out,
                                                128, 50304, 768, 8);
}